// Round 3
// baseline (4903.860 us; speedup 1.0000x reference)
//
#include <hip/hip_runtime.h>
#include <cstdint>
#include <cstddef>

typedef __attribute__((ext_vector_type(8))) short short8;   // 8 bf16 (4 VGPRs)
typedef __attribute__((ext_vector_type(4))) short bfx4;     // 4 bf16 (8 B)
typedef __attribute__((ext_vector_type(4))) float f32x4;

#define HH     100
#define G4     400
#define NCOL   416          // 400 gates + 5 logits + 11 pad = 26 tiles of 16
#define NTIL   26
#define KTN    3            // 3 k-tiles of 32 -> k<96 via MFMA
#define KRES   96           // k=96..99 residual in f32
#define BTOT   8192
#define TST    512
#define GR     16           // rows per phase-group; block owns 2 groups = 32 rows
#define NBLK   256
#define BLOCK  896          // 14 waves: w0-5 G(4-5 tiles), w6 logits+sample, rest E + gumbel
#define NGW    448          // G-crew threads (waves 0..6)
#define NEC    400          // E-crew threads (tid 448..847): 25 cell-groups x 16 rows
#define ZW     420          // z row stride (words)
#define EPW    404          // Ep2 row stride
#define TANHC  1.5f
#define EPSF   1e-9f

__device__ unsigned short d_Bhi[NTIL*KTN*64*8];  // [W_h|W_ops|0] hi, B-frag order
__device__ unsigned short d_Blo[NTIL*KTN*64*8];  // lo residual
__device__ float d_Ep2[6*EPW];                   // emb @ W_x   [e][cell][gate]
__device__ float d_WresG[NCOL*4];                // rows 96..99 of [W_h|W_ops|0], [n][q]
__device__ float d_Z0[(size_t)BTOT*G4];          // x0 @ W_x    [b][n]

static __device__ __forceinline__ unsigned short bf16hi(float f){
  unsigned u = __float_as_uint(f);
  return (unsigned short)((u + 0x7FFFu + ((u>>16)&1u)) >> 16);   // RNE
}
static __device__ __forceinline__ float bf16f(unsigned short s){
  return __uint_as_float(((unsigned)s)<<16);
}
static __device__ __forceinline__ float frcp(float x){ return __builtin_amdgcn_rcpf(x); }
static __device__ __forceinline__ float sigf(float x){ return frcp(1.0f + __expf(-x)); }
static __device__ __forceinline__ float tanh_f(float x){ return 1.0f - 2.0f*frcp(__expf(2.0f*x) + 1.0f); }

// ---- setup kernels -------------------------------------------------------

// B-frag order for 16x16x32: n = tile*16 + (lane&15), k = kt*32 + (lane>>4)*8 + i
__global__ void setup_bpack(const float* __restrict__ Wh, const float* __restrict__ Wops){
  int idx = blockIdx.x*blockDim.x + threadIdx.x;     // NTIL*KTN*64 = 4992
  if (idx >= NTIL*KTN*64) return;
  int tile = idx/(KTN*64), rem = idx - tile*(KTN*64), kt = rem>>6, ln = rem&63;
  int n = tile*16 + (ln & 15);
  #pragma unroll
  for (int i = 0; i < 8; ++i){
    int k = kt*32 + (ln>>4)*8 + i;                   // k < 96 always
    float w = 0.f;
    if (n < G4)          w = Wh[k*G4 + n];
    else if (n < G4+5)   w = Wops[k*5 + (n - G4)];
    unsigned short hi = bf16hi(w);
    unsigned short lo = bf16hi(w - bf16f(hi));
    d_Bhi[idx*8+i] = hi;
    d_Blo[idx*8+i] = lo;
  }
}

__global__ void setup_misc(const float* __restrict__ emb, const float* __restrict__ Wx,
                           const float* __restrict__ Wh, const float* __restrict__ Wops){
  int idx = blockIdx.x*blockDim.x + threadIdx.x;
  if (idx < 6*EPW){                                  // Ep2 [e][cell][gate], stride EPW
    int e = idx/EPW, r2 = idx - e*EPW, je = r2>>2, g = r2&3;
    float s = 0.f;
    if (je < HH)
      for (int k = 0; k < HH; ++k) s = fmaf(emb[e*HH+k], Wx[k*G4 + g*HH + je], s);
    d_Ep2[idx] = s;
  } else if (idx < 6*EPW + NCOL*4){                  // residual rows 96..99
    int i = idx - 6*EPW, n = i>>2, q = i&3;
    float w = 0.f;
    if (n < G4)        w = Wh[(KRES+q)*G4 + n];
    else if (n < G4+5) w = Wops[(KRES+q)*5 + (n - G4)];
    d_WresG[i] = w;
  }
}

// Z0 = x0 @ W_x, stored [b][n]
__global__ __launch_bounds__(256) void setup_z0(const float* __restrict__ x0,
                                                const float* __restrict__ Wx){
  __shared__ float xs[64*101];
  const int bb = blockIdx.x * 64;                    // 128 blocks
  for (int i = threadIdx.x; i < 64*HH; i += 256){
    int r = i/HH, k = i - r*HH;
    xs[r*101 + k] = x0[(size_t)(bb + r)*HH + k];
  }
  __syncthreads();
  const int bl = threadIdx.x & 63;
  for (int ng = threadIdx.x >> 6; ng < HH; ng += 4){
    f32x4 a = {0.f,0.f,0.f,0.f};
    for (int k = 0; k < HH; ++k){
      f32x4 w = *(const f32x4*)&Wx[k*G4 + ng*4];
      a += w * xs[bl*101 + k];
    }
    *(f32x4*)&d_Z0[(size_t)(bb + bl)*G4 + ng*4] = a;
  }
}

// ---- main persistent kernel ---------------------------------------------
// 256 blocks x 32 rows (groups A=rows 0..15, B=16..31), 14 waves, WAVE-SPECIALIZED:
// per phase, G-crew (waves 0..6, MFMA pipe) runs z=h@W + sampling for one group
// while E-crew (tid 448..847, VALU/trans pipe) runs the LSTM elementwise for the
// other group. Roles are fixed -> MFMA waves and trans waves co-schedule on the
// CU (m114 mechanism). Every dependency crosses exactly one barrier:
//   phase(0,t): G(A,t)+sample(A,t-1)  ||  E(B,t-1)  || gumbel(B,t-1)
//   phase(1,t): G(B,t)+sample(B,t-1)  ||  E(A,t)    || gumbel(A,t)
// Logits tile is computed SWAPPED (mfma(W,h) = C^T) so lane r holds row r's
// logits in registers: sampling needs no LDS round-trip.

__global__ __launch_bounds__(BLOCK) void rnn_main(
    const float* __restrict__ u, float* __restrict__ out)
{
  __shared__ __align__(16) float zh[2][GR*ZW];                  // 53760 B
  __shared__ __align__(16) unsigned short fhi[2][KTN*64*8];     //  6144 B
  __shared__ __align__(16) unsigned short flo[2][KTN*64*8];     //  6144 B
  __shared__ __align__(16) float h_res[2][GR*4];                //   512 B [r*4+q]
  __shared__ __align__(16) float Ep2_l[6*EPW];                  //  9696 B
  __shared__ __align__(16) float Wres_l[NCOL*4];                //  6656 B
  __shared__ __align__(16) float gn_lds[2][GR*5];               //   640 B
  __shared__ int op_lds[2][GR];                                 //   128 B

  const int tid  = threadIdx.x;
  const int wave = tid >> 6;
  const int lane = tid & 63;
  const int cn   = lane & 15;
  const int q4   = lane >> 4;
  const int row0 = blockIdx.x * (2*GR);
  const int et   = tid - NGW;       // E-crew index
  const int rE   = et & 15;         // E row within group
  const int cg   = et >> 4;         // E cell-group (0..24), 4 cells each
  const int c0   = cg*4;
  const int gl   = tid - (NGW+NEC); // gumbel spare index (wave 13 lanes 16..35)

  for (int i = tid; i < 6*EPW;  i += BLOCK) Ep2_l[i]  = d_Ep2[i];
  for (int i = tid; i < NCOL*4; i += BLOCK) Wres_l[i] = d_WresG[i];

  // persistent B-fragments: waves 0..4 -> 4 tiles, wave 5 -> 5 tiles (20..24),
  // wave 6 -> logits tile 25 in slot 0.
  short8 bh[5][KTN], bl[5][KTN];
  {
    const short8* bph = (const short8*)d_Bhi;
    const short8* bpl = (const short8*)d_Blo;
    if (wave < 6){
      const int tb = wave*4, ntl = (wave==5) ? 5 : 4;
      #pragma unroll
      for (int tl = 0; tl < 5; ++tl) if (tl < ntl)
        #pragma unroll
        for (int kt = 0; kt < KTN; ++kt){
          int fi = ((tb+tl)*KTN + kt)*64 + lane;
          bh[tl][kt] = bph[fi];
          bl[tl][kt] = bpl[fi];
        }
    } else if (wave == 6){
      #pragma unroll
      for (int kt = 0; kt < KTN; ++kt){
        int fi = (25*KTN + kt)*64 + lane;
        bh[0][kt] = bph[fi];
        bl[0][kt] = bpl[fi];
      }
    }
  }

  float csA[4] = {0.f,0.f,0.f,0.f}, csB[4] = {0.f,0.f,0.f,0.f};
  float lpA=0.f, entA=0.f, lpB=0.f, entB=0.f;

  __syncthreads();

  auto phase = [&](int gG, int t, float* cs, float& lp, float& ent){
    const int  gE    = gG ^ 1;
    const bool stage = (t == 0);
    const bool doE   = gG ? (t < TST) : (t >= 1);
    const bool addE  = gG ? (t >= 1)  : (t >= 2);
    const bool gnDo  = gG ? (t < TST) : (t >= 1);
    const int  uT    = gG ? t : (t-1);

    if (tid < NGW){
      // =============== G-crew ===============
      if (stage){
        for (int k = tid; k < GR*HH; k += NGW){
          int r = k/HH, c4 = k - r*HH;
          *(f32x4*)&zh[gG][r*ZW + c4*4] =
            *(const f32x4*)&d_Z0[(size_t)(row0 + gG*GR + r)*G4 + c4*4];
        }
      } else {
        short8 ah[KTN], al[KTN];                     // A-frags: h of group gG
        #pragma unroll
        for (int kt = 0; kt < KTN; ++kt){
          ah[kt] = *(const short8*)&fhi[gG][(kt*64 + lane)*8];
          al[kt] = *(const short8*)&flo[gG][(kt*64 + lane)*8];
        }
        if (wave < 6){
          f32x4 hq[4];
          #pragma unroll
          for (int i = 0; i < 4; ++i)                // broadcast reads [r][q]
            hq[i] = *(const f32x4*)&h_res[gG][(q4*4+i)*4];
          const int tb = wave*4, ntl = (wave==5) ? 5 : 4;
          #pragma unroll
          for (int tl = 0; tl < 5; ++tl) if (tl < ntl){
            const int n = (tb+tl)*16 + cn;
            f32x4 acc = {0.f,0.f,0.f,0.f};
            #pragma unroll
            for (int kt = 0; kt < KTN; ++kt){
              acc = __builtin_amdgcn_mfma_f32_16x16x32_bf16(ah[kt], bh[tl][kt], acc, 0,0,0);
              acc = __builtin_amdgcn_mfma_f32_16x16x32_bf16(al[kt], bh[tl][kt], acc, 0,0,0);
              acc = __builtin_amdgcn_mfma_f32_16x16x32_bf16(ah[kt], bl[tl][kt], acc, 0,0,0);
              acc = __builtin_amdgcn_mfma_f32_16x16x32_bf16(al[kt], bl[tl][kt], acc, 0,0,0);
            }
            f32x4 wr = *(const f32x4*)&Wres_l[n*4];
            #pragma unroll
            for (int i = 0; i < 4; ++i)
              acc[i] += hq[i].x*wr.x + hq[i].y*wr.y + hq[i].z*wr.z + hq[i].w*wr.w;
            #pragma unroll
            for (int i = 0; i < 4; ++i)              // C: row=q4*4+i, col=n
              zh[gG][(q4*4+i)*ZW + n] = acc[i];
          }
        } else {
          // wave 6: logits tile 25 SWAPPED -> accT[i] = logit[o=q4*4+i][row=cn]
          f32x4 accT = {0.f,0.f,0.f,0.f};
          #pragma unroll
          for (int kt = 0; kt < KTN; ++kt){          // term order = normal path
            accT = __builtin_amdgcn_mfma_f32_16x16x32_bf16(bh[0][kt], ah[kt], accT, 0,0,0);
            accT = __builtin_amdgcn_mfma_f32_16x16x32_bf16(bh[0][kt], al[kt], accT, 0,0,0);
            accT = __builtin_amdgcn_mfma_f32_16x16x32_bf16(bl[0][kt], ah[kt], accT, 0,0,0);
            accT = __builtin_amdgcn_mfma_f32_16x16x32_bf16(bl[0][kt], al[kt], accT, 0,0,0);
          }
          f32x4 hr = *(const f32x4*)&h_res[gG][cn*4];
          #pragma unroll
          for (int i = 0; i < 4; ++i){
            f32x4 wr = *(const f32x4*)&Wres_l[(G4 + q4*4 + i)*4];  // rows >404 are 0
            accT[i] += hr.x*wr.x + hr.y*wr.y + hr.z*wr.z + hr.w*wr.w;
          }
          float l4raw = __shfl_down(accT[0], 16);    // o=4 lives in lane r+16, reg 0
          if (lane < 16){
            const int r = lane;
            float lv[5];
            lv[0] = TANHC*tanh_f(accT[0]);
            lv[1] = TANHC*tanh_f(accT[1]);
            lv[2] = TANHC*tanh_f(accT[2]);
            lv[3] = TANHC*tanh_f(accT[3]);
            lv[4] = TANHC*tanh_f(l4raw);
            int op = 0; float best = -1e30f, lop = lv[0];
            #pragma unroll
            for (int o = 0; o < 5; ++o){
              float v = lv[o] + gn_lds[gG][r*5 + o];
              if (v > best){ best = v; op = o; lop = lv[o]; } // strict >: first-max
            }
            float mx = fmaxf(fmaxf(fmaxf(lv[0],lv[1]), fmaxf(lv[2],lv[3])), lv[4]);
            float se = 0.f;
            #pragma unroll
            for (int o = 0; o < 5; ++o) se += __expf(lv[o] - mx);
            float lse = mx + __logf(se);
            float cur = lse - lop;
            lp  += cur;
            ent += cur * __expf(-cur);
            op_lds[gG][r] = op;
            out[2*BTOT + (size_t)(t-1)*BTOT + row0 + gG*GR + r] = (float)op;
          }
        }
      }
    } else if (et < NEC){
      // =============== E-crew: LSTM elementwise, 4 cells/thread ===============
      if (doE){
        const float* zr = &zh[gE][rE*ZW + c0];
        f32x4 zg0 = *(const f32x4*)&zr[0*HH];
        f32x4 zg1 = *(const f32x4*)&zr[1*HH];
        f32x4 zg2 = *(const f32x4*)&zr[2*HH];
        f32x4 zg3 = *(const f32x4*)&zr[3*HH];
        if (addE){
          const int op = op_lds[gE][rE];
          #pragma unroll
          for (int i = 0; i < 4; ++i){
            f32x4 e4 = *(const f32x4*)&Ep2_l[op*EPW + (c0 + i)*4];
            zg0[i] += e4.x; zg1[i] += e4.y; zg2[i] += e4.z; zg3[i] += e4.w;
          }
        }
        float hv[4];
        #pragma unroll
        for (int i = 0; i < 4; ++i){
          float cn_ = sigf(zg1[i])*cs[i] + sigf(zg0[i])*tanh_f(zg2[i]);
          cs[i] = cn_;
          hv[i] = sigf(zg3[i])*tanh_f(cn_);
        }
        if (cg < 24){                                // cells <96 -> bf16 hi/lo frags
          bfx4 h4, l4;
          #pragma unroll
          for (int i = 0; i < 4; ++i){
            unsigned short hi = bf16hi(hv[i]);
            h4[i] = (short)hi;
            l4[i] = (short)bf16hi(hv[i] - bf16f(hi));
          }
          const int kt   = cg >> 3;
          const int lf   = rE | (((cg >> 1) & 3) << 4);
          const int j0   = (cg & 1) * 4;
          const int base = (kt*64 + lf)*8 + j0;
          *(bfx4*)&fhi[gE][base] = h4;
          *(bfx4*)&flo[gE][base] = l4;
        } else {                                     // cells 96..99 -> f32 residual
          f32x4 hr4 = {hv[0], hv[1], hv[2], hv[3]};
          *(f32x4*)&h_res[gE][rE*4] = hr4;
        }
      }
    } else if (gl >= 0 && gl < 20){
      // =============== gumbel noise for group gE ===============
      if (gnDo){
        f32x4 upr = *(const f32x4*)&u[((size_t)uT*BTOT + row0 + gE*GR)*5 + gl*4];
        f32x4 gv;
        #pragma unroll
        for (int j = 0; j < 4; ++j)
          gv[j] = -__logf(-__logf(upr[j] + EPSF) + EPSF);
        *(f32x4*)&gn_lds[gE][gl*4] = gv;
      }
    }
  };

  for (int t = 0; t <= TST; ++t){
    phase(0, t, csB, lpA, entA);   // G(A,t)+sample(A,t-1) || E(B,t-1) || gn(B)
    __syncthreads();
    phase(1, t, csA, lpB, entB);   // G(B,t)+sample(B,t-1) || E(A,t)   || gn(A)
    if (t == TST) break;
    __syncthreads();
  }

  if (wave == 6 && lane < 16){
    out[row0 + lane]             = lpA;
    out[row0 + GR + lane]        = lpB;
    out[BTOT + row0 + lane]      = entA;
    out[BTOT + row0 + GR + lane] = entB;
  }
}

extern "C" void kernel_launch(void* const* d_in, const int* in_sizes, int n_in,
                              void* d_out, int out_size, void* d_ws, size_t ws_size,
                              hipStream_t stream) {
  const float* x0   = (const float*)d_in[0];
  const float* Wx   = (const float*)d_in[1];
  const float* Wh   = (const float*)d_in[2];
  const float* Wops = (const float*)d_in[3];
  const float* emb  = (const float*)d_in[4];
  const float* u    = (const float*)d_in[5];
  (void)d_ws; (void)ws_size; (void)in_sizes; (void)n_in;

  setup_bpack<<<(NTIL*KTN*64 + 255)/256, 256, 0, stream>>>(Wh, Wops);
  setup_misc<<<(6*EPW + NCOL*4 + 255)/256, 256, 0, stream>>>(emb, Wx, Wh, Wops);
  setup_z0<<<BTOT/64, 256, 0, stream>>>(x0, Wx);
  rnn_main<<<NBLK, BLOCK, 0, stream>>>(u, (float*)d_out);
}

// Round 4
// 2081.269 us; speedup vs baseline: 2.3562x; 2.3562x over previous
//
#include <hip/hip_runtime.h>
#include <cstdint>
#include <cstddef>

typedef __attribute__((ext_vector_type(8))) short short8;   // 8 bf16 (4 VGPRs)
typedef __attribute__((ext_vector_type(4))) short bfx4;     // 4 bf16 (8 B)
typedef __attribute__((ext_vector_type(4))) float f32x4;

#define HH     100
#define G4     400
#define NCOL   416          // 400 gates + 5 logits + 11 pad = 26 tiles of 16
#define NTIL   26
#define KTN    3            // 3 k-tiles of 32 -> k<96 via MFMA
#define KRES   96           // k=96..99 residual in f32
#define BTOT   8192
#define TST    512
#define ROWS   32
#define NBLK   256
#define BLOCK  512          // 8 waves x 64; 2 waves/SIMD -> 256-reg budget/wave
#define ZW     420          // z_lds row stride (words)
#define TANHC  1.5f
#define EPSF   1e-9f

__device__ unsigned short d_Bhi[NTIL*KTN*64*8];  // [W_h|W_ops|0] hi, B-frag order
__device__ unsigned short d_Blo[NTIL*KTN*64*8];  // lo residual
__device__ float d_Ep2[6*G4];                    // emb @ W_x   [e][cell][gate]
__device__ float d_WresG[NCOL*4];                // rows 96..99 of [W_h|W_ops|0], [n][q]
__device__ float d_Z0[(size_t)BTOT*G4];          // x0 @ W_x    [b][n]

static __device__ __forceinline__ unsigned short bf16hi(float f){
  unsigned u = __float_as_uint(f);
  return (unsigned short)((u + 0x7FFFu + ((u>>16)&1u)) >> 16);   // RNE
}
static __device__ __forceinline__ float bf16f(unsigned short s){
  return __uint_as_float(((unsigned)s)<<16);
}
static __device__ __forceinline__ float frcp(float x){ return __builtin_amdgcn_rcpf(x); }
static __device__ __forceinline__ float sigf(float x){ return frcp(1.0f + __expf(-x)); }
static __device__ __forceinline__ float tanh_f(float x){ return 1.0f - 2.0f*frcp(__expf(2.0f*x) + 1.0f); }

// ---- setup kernels (round-0 verbatim) ------------------------------------

// B-frag order for 16x16x32: n = tile*16 + (lane&15), k = kt*32 + (lane>>4)*8 + i
__global__ void setup_bpack(const float* __restrict__ Wh, const float* __restrict__ Wops){
  int idx = blockIdx.x*blockDim.x + threadIdx.x;     // NTIL*KTN*64 = 4992
  if (idx >= NTIL*KTN*64) return;
  int tile = idx/(KTN*64), rem = idx - tile*(KTN*64), kt = rem>>6, ln = rem&63;
  int n = tile*16 + (ln & 15);
  #pragma unroll
  for (int i = 0; i < 8; ++i){
    int k = kt*32 + (ln>>4)*8 + i;                   // k < 96 always
    float w = 0.f;
    if (n < G4)          w = Wh[k*G4 + n];
    else if (n < G4+5)   w = Wops[k*5 + (n - G4)];
    unsigned short hi = bf16hi(w);
    unsigned short lo = bf16hi(w - bf16f(hi));
    d_Bhi[idx*8+i] = hi;
    d_Blo[idx*8+i] = lo;
  }
}

__global__ void setup_misc(const float* __restrict__ emb, const float* __restrict__ Wx,
                           const float* __restrict__ Wh, const float* __restrict__ Wops){
  int idx = blockIdx.x*blockDim.x + threadIdx.x;
  if (idx < 6*G4){                                   // Ep2 [e][cell][gate]
    int e = idx/G4, r2 = idx - e*G4, je = r2>>2, g = r2&3;
    float s = 0.f;
    for (int k = 0; k < HH; ++k) s = fmaf(emb[e*HH+k], Wx[k*G4 + g*HH + je], s);
    d_Ep2[idx] = s;
  } else if (idx < 6*G4 + NCOL*4){                   // residual rows 96..99
    int i = idx - 6*G4, n = i>>2, q = i&3;
    float w = 0.f;
    if (n < G4)        w = Wh[(KRES+q)*G4 + n];
    else if (n < G4+5) w = Wops[(KRES+q)*5 + (n - G4)];
    d_WresG[i] = w;
  }
}

// Z0 = x0 @ W_x, stored [b][n]
__global__ __launch_bounds__(256) void setup_z0(const float* __restrict__ x0,
                                                const float* __restrict__ Wx){
  __shared__ float xs[64*101];
  const int bb = blockIdx.x * 64;                    // 128 blocks
  for (int i = threadIdx.x; i < 64*HH; i += 256){
    int r = i/HH, k = i - r*HH;
    xs[r*101 + k] = x0[(size_t)(bb + r)*HH + k];
  }
  __syncthreads();
  const int bl = threadIdx.x & 63;
  for (int ng = threadIdx.x >> 6; ng < HH; ng += 4){
    f32x4 a = {0.f,0.f,0.f,0.f};
    for (int k = 0; k < HH; ++k){
      f32x4 w = *(const f32x4*)&Wx[k*G4 + ng*4];
      a += w * xs[bl*101 + k];
    }
    *(f32x4*)&d_Z0[(size_t)(bb + bl)*G4 + ng*4] = a;
  }
}

// ---- main persistent kernel ---------------------------------------------
// 256 blocks x 32 rows, 8 waves x 64 = 512 threads, launch_bounds(512,2):
// 2 waves/SIMD -> 256 unified regs/wave. Each wave holds 3-4 persistent
// B-tiles (<=96 regs) -> A-frag LDS re-reads drop from 13x to 8x.
// Tile map: wave0 {23,24,25}+sampling, waves1-5 {3(w-1)..}, wave6 {15..18},
// wave7 {19..22}. E-phase: pass1 = all 512 threads (cells jg*4, jg=tid>>5
// in 0..15); pass2 = tid<256 (jg 16..23) and tid>=480 (jg 24, h_res);
// tid 416..447 do gumbel. Inner code identical to the verified round-0 kernel.

__global__ __launch_bounds__(BLOCK, 2) void rnn_main(
    const float* __restrict__ u, float* __restrict__ out)
{
  __shared__ __align__(16) float z_lds[ROWS*ZW];                // 53760 B
  __shared__ __align__(16) unsigned short fhi[2*KTN*64*8];      //  6144 B
  __shared__ __align__(16) unsigned short flo[2*KTN*64*8];      //  6144 B
  __shared__ __align__(16) float h_res[4*ROWS];                 //   512 B [q][r]
  __shared__ __align__(16) float Ep2_l[6*G4];                   //  9600 B
  __shared__ __align__(16) float Wres_l[NCOL*4];                //  6656 B
  __shared__ __align__(16) float samp[5*36];                    //   720 B
  __shared__ __align__(16) float gn_lds[ROWS*5];                //   640 B
  __shared__ int op_lds[ROWS];

  const int tid  = threadIdx.x;
  const int wave = tid >> 6;
  const int lane = tid & 63;
  const int cn   = lane & 15;       // col-in-tile (B,C) / row-in-tile (A)
  const int q4   = lane >> 4;       // quad
  const int row0 = blockIdx.x * ROWS;
  const int rE   = tid & 31;        // E row

  for (int i = tid; i < 6*G4;   i += BLOCK) Ep2_l[i]  = d_Ep2[i];
  for (int i = tid; i < NCOL*4; i += BLOCK) Wres_l[i] = d_WresG[i];

  // persistent B-fragments, 3-4 tiles per wave
  const int tb  = (wave==0) ? 23 : (wave < 6) ? 3*(wave-1) : 15 + 4*(wave-6);
  const int ntl = (wave >= 6) ? 4 : 3;
  short8 bh[4][KTN], bl[4][KTN];
  {
    const short8* bph = (const short8*)d_Bhi;
    const short8* bpl = (const short8*)d_Blo;
    #pragma unroll
    for (int tl = 0; tl < 4; ++tl) if (tl < ntl)
      #pragma unroll
      for (int kt = 0; kt < KTN; ++kt){
        int fi = ((tb+tl)*KTN + kt)*64 + lane;
        bh[tl][kt] = bph[fi];
        bl[tl][kt] = bpl[fi];
      }
  }

  float cs1[4] = {0.f,0.f,0.f,0.f};   // pass-1 cells (jg 0..15)
  float cs2[4] = {0.f,0.f,0.f,0.f};   // pass-2 cells (jg 16..24)
  float lp_acc = 0.f, ent_acc = 0.f;

  for (int t = 0; t <= TST; ++t){
    // gumbel u prefetch (tid 416..447); HBM latency hides under G+E
    float upr[5];
    if (t < TST && tid >= 416 && tid < 448){
      const float* up = u + ((size_t)t*BTOT + row0 + (tid - 416))*5;
      #pragma unroll
      for (int o = 0; o < 5; ++o) upr[o] = up[o];
    }

    if (t == 0){
      // stage z_0 = x0 @ W_x (gates only)
      for (int i = tid; i < ROWS*HH; i += BLOCK){
        int r = i/HH, c4 = i - r*HH;
        *(f32x4*)&z_lds[r*ZW + c4*4] =
          *(const f32x4*)&d_Z0[(size_t)(row0 + r)*G4 + c4*4];
      }
    } else {
      // ---- G: z_t = h_t @ [W_h|W_ops]  (MFMA k<96 + f32 residual) ----
      #pragma unroll
      for (int mt = 0; mt < 2; ++mt){
        short8 ah[KTN], al[KTN];
        #pragma unroll
        for (int kt = 0; kt < KTN; ++kt){
          ah[kt] = *(const short8*)&fhi[((mt*KTN + kt)*64 + lane)*8];
          al[kt] = *(const short8*)&flo[((mt*KTN + kt)*64 + lane)*8];
        }
        f32x4 hq[4];
        #pragma unroll
        for (int q = 0; q < 4; ++q)                       // broadcast reads
          hq[q] = *(const f32x4*)&h_res[q*ROWS + mt*16 + q4*4];
        #pragma unroll
        for (int tl = 0; tl < 4; ++tl) if (tl < ntl){
          const int n = (tb+tl)*16 + cn;
          f32x4 acc = {0.f,0.f,0.f,0.f};
          #pragma unroll
          for (int kt = 0; kt < KTN; ++kt){
            acc = __builtin_amdgcn_mfma_f32_16x16x32_bf16(ah[kt], bh[tl][kt], acc, 0,0,0);
            acc = __builtin_amdgcn_mfma_f32_16x16x32_bf16(al[kt], bh[tl][kt], acc, 0,0,0);
            acc = __builtin_amdgcn_mfma_f32_16x16x32_bf16(ah[kt], bl[tl][kt], acc, 0,0,0);
            acc = __builtin_amdgcn_mfma_f32_16x16x32_bf16(al[kt], bl[tl][kt], acc, 0,0,0);
          }
          f32x4 wr = *(const f32x4*)&Wres_l[n*4];
          #pragma unroll
          for (int q = 0; q < 4; ++q) acc += hq[q] * wr[q];
          const int rowb = mt*16 + q4*4;                  // C: row=q4*4+reg, col=cn
          #pragma unroll
          for (int i = 0; i < 4; ++i)
            z_lds[(rowb + i)*ZW + n] = acc[i];
          if (wave == 0 && tl == 2 && cn < 5)             // logits cols 400..404
            *(f32x4*)&samp[cn*36 + mt*16 + q4*4] = acc;
        }
      }
      // ---- sampling for step t-1 (wave 0; same-wave LDS dep) ----
      if (wave == 0 && lane < 32){
        int r = lane;
        float l[5];
        #pragma unroll
        for (int o = 0; o < 5; ++o) l[o] = TANHC * tanh_f(samp[o*36 + r]);
        int op = 0; float best = -1e30f;
        #pragma unroll
        for (int o = 0; o < 5; ++o){
          float v = l[o] + gn_lds[r*5 + o];
          if (v > best){ best = v; op = o; }              // strict >: first-max ties
        }
        float mx = fmaxf(fmaxf(fmaxf(l[0],l[1]), fmaxf(l[2],l[3])), l[4]);
        float se = 0.f;
        #pragma unroll
        for (int o = 0; o < 5; ++o) se += __expf(l[o] - mx);
        float lse = mx + __logf(se);
        float cur = lse - l[op];
        lp_acc  += cur;
        ent_acc += cur * __expf(-cur);
        op_lds[r] = op;
        out[2*BTOT + (size_t)(t-1)*BTOT + row0 + r] = (float)op;
      }
    }
    if (t == TST) break;
    __syncthreads();   // b1: z_t + op_{t-1} ready

    // ---- E: LSTM elementwise (round-0 body), two passes over cell-groups ----
    // pass 1: all threads, jg = tid>>5 in 0..15 (cells 0..63)
    {
      const int jg = tid >> 5;
      f32x4 zg[4];
      #pragma unroll
      for (int g = 0; g < 4; ++g)
        zg[g] = *(const f32x4*)&z_lds[rE*ZW + g*HH + jg*4];
      if (t > 0){
        const int op = op_lds[rE];
        #pragma unroll
        for (int i = 0; i < 4; ++i){
          f32x4 e4 = *(const f32x4*)&Ep2_l[op*G4 + (jg*4 + i)*4];
          zg[0][i] += e4.x; zg[1][i] += e4.y; zg[2][i] += e4.z; zg[3][i] += e4.w;
        }
      }
      float hv[4];
      #pragma unroll
      for (int i = 0; i < 4; ++i){
        float cn_ = sigf(zg[1][i])*cs1[i] + sigf(zg[0][i])*tanh_f(zg[2][i]);
        cs1[i] = cn_;
        hv[i] = sigf(zg[3][i])*tanh_f(cn_);
      }
      bfx4 h4, l4;                                       // jg<16 -> always frags
      #pragma unroll
      for (int i = 0; i < 4; ++i){
        unsigned short hi = bf16hi(hv[i]);
        h4[i] = (short)hi;
        l4[i] = (short)bf16hi(hv[i] - bf16f(hi));
      }
      const int kt   = jg >> 3;
      const int lf   = (rE & 15) | (((jg >> 1) & 3) << 4);
      const int mt   = rE >> 4;
      const int j0   = (jg & 1) * 4;
      const int base = ((mt*KTN + kt)*64 + lf)*8 + j0;
      *(bfx4*)&fhi[base] = h4;
      *(bfx4*)&flo[base] = l4;
    }
    // pass 2: tid<256 -> jg 16..23 (frags); tid>=480 -> jg 24 (h_res);
    // tid 416..447 -> gumbel noise
    if (tid < 256 || tid >= 480){
      const int jg = (tid < 256) ? (16 + (tid >> 5)) : 24;
      const int c0 = jg*4;
      f32x4 zg[4];
      #pragma unroll
      for (int g = 0; g < 4; ++g)
        zg[g] = *(const f32x4*)&z_lds[rE*ZW + g*HH + c0];
      if (t > 0){
        const int op = op_lds[rE];
        #pragma unroll
        for (int i = 0; i < 4; ++i){
          f32x4 e4 = *(const f32x4*)&Ep2_l[op*G4 + (c0 + i)*4];
          zg[0][i] += e4.x; zg[1][i] += e4.y; zg[2][i] += e4.z; zg[3][i] += e4.w;
        }
      }
      float hv[4];
      #pragma unroll
      for (int i = 0; i < 4; ++i){
        float cn_ = sigf(zg[1][i])*cs2[i] + sigf(zg[0][i])*tanh_f(zg[2][i]);
        cs2[i] = cn_;
        hv[i] = sigf(zg[3][i])*tanh_f(cn_);
      }
      if (tid < 256){                                    // jg 16..23 -> frags
        bfx4 h4, l4;
        #pragma unroll
        for (int i = 0; i < 4; ++i){
          unsigned short hi = bf16hi(hv[i]);
          h4[i] = (short)hi;
          l4[i] = (short)bf16hi(hv[i] - bf16f(hi));
        }
        const int kt   = jg >> 3;                        // = 2
        const int lf   = (rE & 15) | (((jg >> 1) & 3) << 4);
        const int mt   = rE >> 4;
        const int j0   = (jg & 1) * 4;
        const int base = ((mt*KTN + kt)*64 + lf)*8 + j0;
        *(bfx4*)&fhi[base] = h4;
        *(bfx4*)&flo[base] = l4;
      } else {                                           // jg==24: k=96..99 residual
        #pragma unroll
        for (int i = 0; i < 4; ++i) h_res[i*ROWS + rE] = hv[i];
      }
    } else if (tid >= 416 && tid < 448){
      // gumbel noise for u[t] (consumed at G_{t+1}); loads issued at loop top
      int r = tid - 416;
      #pragma unroll
      for (int o = 0; o < 5; ++o)
        gn_lds[r*5 + o] = -__logf(-__logf(upr[o] + EPSF) + EPSF);
    }
    __syncthreads();   // b2: h_{t+1} frags + h_res + gn ready
  }

  if (wave == 0 && lane < 32){
    out[row0 + lane]        = lp_acc;
    out[BTOT + row0 + lane] = ent_acc;
  }
}

extern "C" void kernel_launch(void* const* d_in, const int* in_sizes, int n_in,
                              void* d_out, int out_size, void* d_ws, size_t ws_size,
                              hipStream_t stream) {
  const float* x0   = (const float*)d_in[0];
  const float* Wx   = (const float*)d_in[1];
  const float* Wh   = (const float*)d_in[2];
  const float* Wops = (const float*)d_in[3];
  const float* emb  = (const float*)d_in[4];
  const float* u    = (const float*)d_in[5];
  (void)d_ws; (void)ws_size; (void)in_sizes; (void)n_in;

  setup_bpack<<<(NTIL*KTN*64 + 255)/256, 256, 0, stream>>>(Wh, Wops);
  setup_misc<<<(6*G4 + NCOL*4 + 255)/256, 256, 0, stream>>>(emb, Wx, Wh, Wops);
  setup_z0<<<BTOT/64, 256, 0, stream>>>(x0, Wx);
  rnn_main<<<NBLK, BLOCK, 0, stream>>>(u, (float*)d_out);
}